// Round 6
// baseline (322.303 us; speedup 1.0000x reference)
//
#include <hip/hip_runtime.h>

#define EDGES 400000
#define NN 25000
#define NCH 288
#define EPB 32
#define NBLK (EDGES / EPB)
#define NBIN_PAD 25024

#define W1FRAG 16384   // 2 k2 * 16 nt * 64 lane * 8 el
#define W2FRAG 24576   // 8 k8 * 6 nt * 64 lane * 8 el

typedef float f32x4 __attribute__((ext_vector_type(4)));
typedef short short8 __attribute__((ext_vector_type(8)));

__device__ __forceinline__ unsigned short f2bf(float x) {          // RNE
    unsigned u = __float_as_uint(x);
    unsigned r = (u + 0x7fffu + ((u >> 16) & 1u)) >> 16;
    return (unsigned short)r;
}
__device__ __forceinline__ unsigned short f2bf_t(float x) {        // truncate
    return (unsigned short)(__float_as_uint(x) >> 16);
}
__device__ __forceinline__ float bf2f(unsigned short h) {
    return __uint_as_float(((unsigned)h) << 16);
}
// pack 2 f32 -> 2 bf16 (RNE), lo half = first operand
__device__ __forceinline__ unsigned cvtpk(float a, float b) {
    unsigned r;
    asm("v_cvt_pk_bf16_f32 %0, %1, %2" : "=v"(r) : "v"(a), "v"(b));
    return r;
}

// ---------------- weight -> fragment-order bf16 hi/lo precompute ----------------
__global__ void k_wfrag(const float* __restrict__ W1, const float* __restrict__ W2,
                        unsigned short* __restrict__ w1h, unsigned short* __restrict__ w1l,
                        unsigned short* __restrict__ w2h, unsigned short* __restrict__ w2l) {
    int i = blockIdx.x * 256 + threadIdx.x;
    if (i < W1FRAG) {
        int j = i & 7, l = (i >> 3) & 63, nt = (i >> 9) & 15, k2 = (i >> 13) & 1;
        int n = nt * 16 + (l & 15), k = k2 * 32 + ((l >> 4) * 8) + j;
        float v = W1[k * 256 + n] * 0.125f;              // fold 1/sqrt(64)
        unsigned short hb = f2bf(v);
        w1h[i] = hb; w1l[i] = f2bf_t(v - bf2f(hb));
    } else if (i < W1FRAG + W2FRAG) {
        int i2 = i - W1FRAG;
        int j = i2 & 7, l = (i2 >> 3) & 63, r = i2 >> 9;  // r in [0,48)
        int nt = r % 6, k8 = r / 6;
        int n = nt * 16 + (l & 15), k = k8 * 32 + ((l >> 4) * 8) + j;
        float v = W2[k * 96 + n] * 0.015625f;            // fold 1/sqrt(256)*1/sqrt(16)
        unsigned short hb = f2bf(v);
        w2h[i2] = hb; w2l[i2] = f2bf_t(v - bf2f(hb));
    }
}

// ---------------- counting sort (dst-ordered edges) ----------------
__global__ void k_hist(const int* __restrict__ edst, unsigned* __restrict__ cnt) {
    int i = blockIdx.x * 256 + threadIdx.x;
    if (i < EDGES) atomicAdd(&cnt[edst[i]], 1u);
}

__global__ __launch_bounds__(1024) void k_scan(const unsigned* __restrict__ cnt,
                                               unsigned* __restrict__ cur) {
    __shared__ unsigned s_wt[16];
    __shared__ unsigned s_carry;
    const int t = threadIdx.x, lane = t & 63, wid = t >> 6;
    if (t == 0) s_carry = 0u;
    __syncthreads();
    for (int base = 0; base < NN; base += 1024) {
        int i = base + t;
        unsigned v = (i < NN) ? cnt[i] : 0u;
        unsigned incl = v;
        #pragma unroll
        for (int d = 1; d < 64; d <<= 1) {
            unsigned u = __shfl_up(incl, d);
            if (lane >= d) incl += u;
        }
        if (lane == 63) s_wt[wid] = incl;
        __syncthreads();
        if (wid == 0 && lane < 16) {
            unsigned wincl = s_wt[lane];
            #pragma unroll
            for (int d = 1; d < 16; d <<= 1) {
                unsigned u = __shfl_up(wincl, d);
                if (lane >= d) wincl += u;
            }
            s_wt[lane] = wincl;
        }
        __syncthreads();
        unsigned waveoff = (wid > 0) ? s_wt[wid - 1] : 0u;
        unsigned carry = s_carry;
        if (i < NN) cur[i] = carry + waveoff + incl - v;
        __syncthreads();
        if (t == 1023) s_carry = carry + s_wt[15];
        __syncthreads();
    }
}

__global__ void k_perm(const int* __restrict__ edst, unsigned* __restrict__ cur,
                       unsigned* __restrict__ perm) {
    int i = blockIdx.x * 256 + threadIdx.x;
    if (i < EDGES) {
        unsigned p = atomicAdd(&cur[edst[i]], 1u);
        perm[p] = (unsigned)i;
    }
}

// ---------------- fused MFMA conv ----------------
struct SMem {
    union {
        struct {
            unsigned short a1h[EPB * 64];   // 4 KB  etype hi [e][k], swizzled
            unsigned short a1l[EPB * 64];   // 4 KB  etype lo
            unsigned short a2h[EPB * 64];   // 4 KB  h quarter hi [e][k-local]
            unsigned short a2l[EPB * 64];   // 4 KB  h quarter lo
        };
        float sw[EPB * 100];                // 12.8 KB overlay after MFMA phases
    };
};

template <bool SORTED>
__global__ __launch_bounds__(256) void conv_mfma(
    const int* __restrict__ esrc, const int* __restrict__ edst,
    const float* __restrict__ nemb, const float* __restrict__ etype,
    const unsigned short* __restrict__ w1h, const unsigned short* __restrict__ w1l,
    const unsigned short* __restrict__ w2h, const unsigned short* __restrict__ w2l,
    const unsigned* __restrict__ perm,
    float* __restrict__ out)
{
    __shared__ SMem U;                         // 16 KB
    __shared__ float geom[EPB][2][9];          // 2.25 KB
    __shared__ int s_eidx[EPB], s_dst[EPB];
    __shared__ unsigned s_mask;

    const int t = threadIdx.x;
    const int lane = t & 63, w = t >> 6;
    const int g = lane >> 4, ln15 = lane & 15;
    const size_t slot0 = (size_t)blockIdx.x * EPB;

    if (t < EPB) {
        int e = SORTED ? (int)perm[slot0 + t] : (int)(slot0 + t);
        s_eidx[t] = e;
        s_dst[t] = edst[e];
    }
    __syncthreads();

    // ---- stage etype tile -> bf16 hi/lo in LDS (XOR-swizzled [e][k] rows) ----
    #pragma unroll
    for (int i = 0; i < 2; ++i) {
        int f4 = t + 256 * i;                  // 0..511
        int row = f4 >> 4, q = f4 & 15;
        const float4* src = (const float4*)(etype + (size_t)s_eidx[row] * 64);
        float4 v = src[q];
        unsigned hp01 = cvtpk(v.x, v.y), hp23 = cvtpk(v.z, v.w);
        float lo0 = v.x - __uint_as_float(hp01 << 16);
        float lo1 = v.y - __uint_as_float(hp01 & 0xffff0000u);
        float lo2 = v.z - __uint_as_float(hp23 << 16);
        float lo3 = v.w - __uint_as_float(hp23 & 0xffff0000u);
        unsigned lp01 = cvtpk(lo0, lo1), lp23 = cvtpk(lo2, lo3);
        int boff = row * 128 + ((q * 8) ^ ((row & 7) << 4));
        *(uint2*)((char*)U.a1h + boff) = make_uint2(hp01, hp23);
        *(uint2*)((char*)U.a1l + boff) = make_uint2(lp01, lp23);
    }
    // ---- geometry (threads 0..63) ----
    if (t < EPB * 2) {
        int e = t >> 1, b = t & 1;
        int sn = esrc[s_eidx[e]], dn = s_dst[e];
        const float* xp = nemb + ((size_t)b * NN + sn) * 3;
        const float* yp = nemb + ((size_t)b * NN + dn) * 3;
        float x0 = xp[0], x1 = xp[1], x2 = xp[2];
        float y0 = yp[0], y1 = yp[1], y2 = yp[2];
        const float inv3 = 0.5773502691896258f;
        const float inv2 = 0.7071067811865476f;
        const float inv6 = 0.4082482904638630f;
        geom[e][b][0] = (x0*y0 + x1*y1 + x2*y2) * inv3;
        geom[e][b][1] = (x1*y2 - x2*y1) * inv2;
        geom[e][b][2] = (x2*y0 - x0*y2) * inv2;
        geom[e][b][3] = (x0*y1 - x1*y0) * inv2;
        geom[e][b][4] = (x0*y1 + x1*y0) * inv2;
        geom[e][b][5] = (x1*y2 + x2*y1) * inv2;
        geom[e][b][6] = (x0*y2 + x2*y0) * inv2;
        geom[e][b][7] = (x0*y0 - x1*y1) * inv2;
        geom[e][b][8] = (2.0f*x2*y2 - x0*y0 - x1*y1) * inv6;
    } else if (t < 128) {
        // ---- run-boundary mask (wave 1) ----
        int l = t - 64, e = l & 31;
        bool flag = (e > 0) && (s_dst[e] != s_dst[e - 1]);
        unsigned long long bal = __ballot(flag);
        if (l == 0) s_mask = (unsigned)bal;
    }
    __syncthreads();

    // layer-2 accumulators persist across all four quarters
    const int m2 = w >> 1, nb = 3 * (w & 1);
    f32x4 acc2[3];
    #pragma unroll
    for (int n = 0; n < 3; ++n)
        #pragma unroll
        for (int r = 0; r < 4; ++r) acc2[n][r] = 0.f;

    #pragma unroll
    for (int qt = 0; qt < 4; ++qt) {
        // ---- layer 1 (quarter), transposed: D[n][e] = W1^T x etype^T ----
        // wave w owns n-tile nt = 4*qt + w; lane holds n = nt*16 + g*4 + r, e-tile m
        f32x4 acc1[2];
        #pragma unroll
        for (int m = 0; m < 2; ++m)
            #pragma unroll
            for (int r = 0; r < 4; ++r) acc1[m][r] = 0.f;

        #pragma unroll
        for (int k2 = 0; k2 < 2; ++k2) {
            int idx = ((k2 * 16 + 4 * qt + w) * 64 + lane) * 8;
            short8 wah = *(const short8*)(w1h + idx);   // A-operand (W1 frag)
            short8 wal = *(const short8*)(w1l + idx);
            #pragma unroll
            for (int m = 0; m < 2; ++m) {
                int row = m * 16 + ln15;
                int boff = row * 128 + (((k2 * 64) + g * 16) ^ ((row & 7) << 4));
                short8 eth = *(const short8*)((const char*)U.a1h + boff);  // B-operand
                short8 etl = *(const short8*)((const char*)U.a1l + boff);
                acc1[m] = __builtin_amdgcn_mfma_f32_16x16x32_bf16(wah, eth, acc1[m], 0, 0, 0);
                acc1[m] = __builtin_amdgcn_mfma_f32_16x16x32_bf16(wal, eth, acc1[m], 0, 0, 0);
                acc1[m] = __builtin_amdgcn_mfma_f32_16x16x32_bf16(wah, etl, acc1[m], 0, 0, 0);
            }
        }

        // ---- silu + packed split -> h quarter [e][k-local] (uint2 stores) ----
        #pragma unroll
        for (int m = 0; m < 2; ++m) {
            float s0, s1, s2, s3;
            {
                float p0 = acc1[m][0], p1 = acc1[m][1], p2 = acc1[m][2], p3 = acc1[m][3];
                s0 = p0 * __builtin_amdgcn_rcpf(1.f + __expf(-p0));
                s1 = p1 * __builtin_amdgcn_rcpf(1.f + __expf(-p1));
                s2 = p2 * __builtin_amdgcn_rcpf(1.f + __expf(-p2));
                s3 = p3 * __builtin_amdgcn_rcpf(1.f + __expf(-p3));
            }
            unsigned hp0 = cvtpk(s0, s1), hp1 = cvtpk(s2, s3);
            float lo0 = s0 - __uint_as_float(hp0 << 16);
            float lo1 = s1 - __uint_as_float(hp0 & 0xffff0000u);
            float lo2 = s2 - __uint_as_float(hp1 << 16);
            float lo3 = s3 - __uint_as_float(hp1 & 0xffff0000u);
            unsigned lp0 = cvtpk(lo0, lo1), lp1 = cvtpk(lo2, lo3);
            int e = m * 16 + ln15;                       // lane's e-col
            int boff = e * 128 + ((w * 32 + g * 8) ^ ((ln15 & 7) << 4));
            *(uint2*)((char*)U.a2h + boff) = make_uint2(hp0, hp1);
            *(uint2*)((char*)U.a2l + boff) = make_uint2(lp0, lp1);
        }
        __syncthreads();

        // ---- layer 2 (quarter): k-steps kg = 2*qt, 2*qt+1 ----
        #pragma unroll
        for (int kk = 0; kk < 2; ++kk) {
            int kg = 2 * qt + kk;
            short8 bh[3], bl[3];
            #pragma unroll
            for (int n = 0; n < 3; ++n) {
                int idx = ((kg * 6 + nb + n) * 64 + lane) * 8;
                bh[n] = *(const short8*)(w2h + idx);
                bl[n] = *(const short8*)(w2l + idx);
            }
            int row = m2 * 16 + ln15;
            int boff = row * 128 + ((kk * 64 + g * 16) ^ ((ln15 & 7) << 4));
            short8 ah = *(const short8*)((const char*)U.a2h + boff);
            short8 al = *(const short8*)((const char*)U.a2l + boff);
            #pragma unroll
            for (int n = 0; n < 3; ++n) {
                acc2[n] = __builtin_amdgcn_mfma_f32_16x16x32_bf16(ah, bh[n], acc2[n], 0, 0, 0);
                acc2[n] = __builtin_amdgcn_mfma_f32_16x16x32_bf16(ah, bl[n], acc2[n], 0, 0, 0);
                acc2[n] = __builtin_amdgcn_mfma_f32_16x16x32_bf16(al, bh[n], acc2[n], 0, 0, 0);
            }
        }
        __syncthreads();   // a2 consumed; next quarter overwrites
    }

    // ---- write w to LDS (overlays the whole dead union; padded stride 100) ----
    #pragma unroll
    for (int n = 0; n < 3; ++n) {
        int c = (nb + n) * 16 + ln15;
        #pragma unroll
        for (int r = 0; r < 4; ++r) {
            int e = m2 * 16 + g * 4 + r;
            U.sw[e * 100 + c] = acc2[n][r];
        }
    }
    __syncthreads();

    // ---- tensor product + run-grouped scatter (SGPR boundary mask) ----
    {
        unsigned mask = __builtin_amdgcn_readfirstlane(s_mask);
        for (int idx = t; idx < NCH * 2; idx += 256) {
            int b = idx >= NCH;
            int c = idx - b * NCH;
            unsigned wi, gi;
            if (c < 32)       { wi = c;                          gi = 0; }
            else if (c < 128) { unsigned q = c - 32;  wi = 32 + q / 3u; gi = 1 + q % 3u; }
            else              { unsigned q = c - 128; wi = 64 + q / 5u; gi = 4 + q % 5u; }
            float* base = out + (size_t)b * NN * NCH + c;
            float acc = 0.f;
            int rs = 0;
            #pragma unroll
            for (int e = 0; e < EPB; ++e) {
                if (e && (mask & (1u << e))) {             // uniform scalar test
                    float* addr = base + (size_t)s_dst[e - 1] * NCH;
                    if (SORTED && rs > 0) *addr = acc;     // interior run: exclusive
                    else atomicAdd(addr, acc);             // boundary run
                    acc = 0.f; rs = e;
                }
                acc = fmaf(U.sw[e * 100 + wi], geom[e][b][gi], acc);
            }
            atomicAdd(base + (size_t)s_dst[EPB - 1] * NCH, acc);   // last run
        }
    }
}

extern "C" void kernel_launch(void* const* d_in, const int* in_sizes, int n_in,
                              void* d_out, int out_size, void* d_ws, size_t ws_size,
                              hipStream_t stream) {
    const int*   esrc  = (const int*)d_in[0];
    const int*   edst  = (const int*)d_in[1];
    const float* nemb  = (const float*)d_in[2];
    const float* etype = (const float*)d_in[3];
    const float* W1    = (const float*)d_in[4];
    const float* W2    = (const float*)d_in[5];
    float* out = (float*)d_out;

    hipMemsetAsync(out, 0, (size_t)out_size * sizeof(float), stream);

    unsigned short* w1h = (unsigned short*)d_ws;
    unsigned short* w1l = w1h + W1FRAG;
    unsigned short* w2h = w1l + W1FRAG;
    unsigned short* w2l = w2h + W2FRAG;
    const size_t frag_bytes = (size_t)(2 * W1FRAG + 2 * W2FRAG) * sizeof(unsigned short);

    k_wfrag<<<(W1FRAG + W2FRAG + 255) / 256, 256, 0, stream>>>(W1, W2, w1h, w1l, w2h, w2l);

    const size_t sort_bytes = (size_t)(2 * NBIN_PAD + EDGES) * sizeof(unsigned);
    if (ws_size >= frag_bytes + sort_bytes) {
        unsigned* cnt  = (unsigned*)((char*)d_ws + frag_bytes);
        unsigned* cur  = cnt + NBIN_PAD;
        unsigned* perm = cur + NBIN_PAD;
        hipMemsetAsync(cnt, 0, NBIN_PAD * sizeof(unsigned), stream);
        k_hist<<<(EDGES + 255) / 256, 256, 0, stream>>>(edst, cnt);
        k_scan<<<1, 1024, 0, stream>>>(cnt, cur);
        k_perm<<<(EDGES + 255) / 256, 256, 0, stream>>>(edst, cur, perm);
        conv_mfma<true><<<NBLK, 256, 0, stream>>>(
            esrc, edst, nemb, etype, w1h, w1l, w2h, w2l, perm, out);
    } else {
        conv_mfma<false><<<NBLK, 256, 0, stream>>>(
            esrc, edst, nemb, etype, w1h, w1l, w2h, w2l, nullptr, out);
    }
}

// Round 7
// 284.687 us; speedup vs baseline: 1.1321x; 1.1321x over previous
//
#include <hip/hip_runtime.h>

#define EDGES 400000
#define NN 25000
#define NCH 288
#define EPB 32
#define NBLK (EDGES / EPB)
#define NBIN_PAD 25024

#define W1FRAG 16384   // 2 k2 * 16 nt * 64 lane * 8 el
#define W2FRAG 24576   // 8 k8 * 6 nt * 64 lane * 8 el

typedef float f32x4 __attribute__((ext_vector_type(4)));
typedef short short8 __attribute__((ext_vector_type(8)));

__device__ __forceinline__ unsigned short f2bf(float x) {          // RNE
    unsigned u = __float_as_uint(x);
    unsigned r = (u + 0x7fffu + ((u >> 16) & 1u)) >> 16;
    return (unsigned short)r;
}
__device__ __forceinline__ unsigned short f2bf_t(float x) {        // truncate
    return (unsigned short)(__float_as_uint(x) >> 16);
}
__device__ __forceinline__ float bf2f(unsigned short h) {
    return __uint_as_float(((unsigned)h) << 16);
}
// pack 2 f32 -> 2 bf16 (RNE), first operand in low half
__device__ __forceinline__ unsigned cvtpk(float a, float b) {
    unsigned r;
    asm("v_cvt_pk_bf16_f32 %0, %1, %2" : "=v"(r) : "v"(a), "v"(b));
    return r;
}
__device__ __forceinline__ float lowf(unsigned u)  { return __uint_as_float(u << 16); }
__device__ __forceinline__ float highf(unsigned u) { return __uint_as_float(u & 0xffff0000u); }
__device__ __forceinline__ short8 mk8(unsigned a, unsigned b, unsigned c, unsigned d) {
    union { unsigned u[4]; short8 s; } x;
    x.u[0] = a; x.u[1] = b; x.u[2] = c; x.u[3] = d;
    return x.s;
}

// ---------------- weight -> fragment-order bf16 hi/lo precompute ----------------
__global__ void k_wfrag(const float* __restrict__ W1, const float* __restrict__ W2,
                        unsigned short* __restrict__ w1h, unsigned short* __restrict__ w1l,
                        unsigned short* __restrict__ w2h, unsigned short* __restrict__ w2l) {
    int i = blockIdx.x * 256 + threadIdx.x;
    if (i < W1FRAG) {
        int j = i & 7, l = (i >> 3) & 63, nt = (i >> 9) & 15, k2 = (i >> 13) & 1;
        int n = nt * 16 + (l & 15), k = k2 * 32 + ((l >> 4) * 8) + j;
        float v = W1[k * 256 + n] * 0.125f;              // fold 1/sqrt(64)
        unsigned short hb = f2bf(v);
        w1h[i] = hb; w1l[i] = f2bf_t(v - bf2f(hb));
    } else if (i < W1FRAG + W2FRAG) {
        int i2 = i - W1FRAG;
        int j = i2 & 7, l = (i2 >> 3) & 63, r = i2 >> 9;  // r in [0,48)
        int nt = r % 6, k8 = r / 6;
        int n = nt * 16 + (l & 15), k = k8 * 32 + ((l >> 4) * 8) + j;
        float v = W2[k * 96 + n] * 0.015625f;            // fold 1/sqrt(256)*1/sqrt(16)
        unsigned short hb = f2bf(v);
        w2h[i2] = hb; w2l[i2] = f2bf_t(v - bf2f(hb));
    }
}

// ---------------- counting sort (dst-ordered edges) ----------------
__global__ void k_hist(const int* __restrict__ edst, unsigned* __restrict__ cnt) {
    int i = blockIdx.x * 256 + threadIdx.x;
    if (i < EDGES) atomicAdd(&cnt[edst[i]], 1u);
}

__global__ __launch_bounds__(1024) void k_scan(const unsigned* __restrict__ cnt,
                                               unsigned* __restrict__ cur) {
    __shared__ unsigned s_wt[16];
    __shared__ unsigned s_carry;
    const int t = threadIdx.x, lane = t & 63, wid = t >> 6;
    if (t == 0) s_carry = 0u;
    __syncthreads();
    for (int base = 0; base < NN; base += 1024) {
        int i = base + t;
        unsigned v = (i < NN) ? cnt[i] : 0u;
        unsigned incl = v;
        #pragma unroll
        for (int d = 1; d < 64; d <<= 1) {
            unsigned u = __shfl_up(incl, d);
            if (lane >= d) incl += u;
        }
        if (lane == 63) s_wt[wid] = incl;
        __syncthreads();
        if (wid == 0 && lane < 16) {
            unsigned wincl = s_wt[lane];
            #pragma unroll
            for (int d = 1; d < 16; d <<= 1) {
                unsigned u = __shfl_up(wincl, d);
                if (lane >= d) wincl += u;
            }
            s_wt[lane] = wincl;
        }
        __syncthreads();
        unsigned waveoff = (wid > 0) ? s_wt[wid - 1] : 0u;
        unsigned carry = s_carry;
        if (i < NN) cur[i] = carry + waveoff + incl - v;
        __syncthreads();
        if (t == 1023) s_carry = carry + s_wt[15];
        __syncthreads();
    }
}

__global__ void k_perm(const int* __restrict__ edst, unsigned* __restrict__ cur,
                       unsigned* __restrict__ perm) {
    int i = blockIdx.x * 256 + threadIdx.x;
    if (i < EDGES) {
        unsigned p = atomicAdd(&cur[edst[i]], 1u);
        perm[p] = (unsigned)i;
    }
}

// ---------------- fused MFMA conv ----------------
struct SMem {
    union {
        struct __align__(16) {
            unsigned short a2h[EPB * 64];   // 4 KB  h quarter hi, swizzled
            unsigned short a2l[EPB * 64];   // 4 KB  h quarter lo
        };
        float sw[96 * 36];                  // 13.8 KB  w transposed [c][e], stride 36
    };
};

template <bool SORTED>
__global__ __launch_bounds__(256) void conv_mfma(
    const int* __restrict__ esrc, const int* __restrict__ edst,
    const float* __restrict__ nemb, const float* __restrict__ etype,
    const unsigned short* __restrict__ w1h, const unsigned short* __restrict__ w1l,
    const unsigned short* __restrict__ w2h, const unsigned short* __restrict__ w2l,
    const unsigned* __restrict__ perm,
    float* __restrict__ out)
{
    __shared__ SMem U;                            // 13.8 KB
    __shared__ __align__(16) float geom_t[2][9][EPB];  // 2.25 KB, [b][gi][e]
    __shared__ int s_eidx[EPB], s_dst[EPB];
    __shared__ unsigned s_mask;

    const int t = threadIdx.x;
    const int lane = t & 63, w = t >> 6;
    const int g = lane >> 4, ln15 = lane & 15;
    const size_t slot0 = (size_t)blockIdx.x * EPB;

    if (t < EPB) {
        int e = SORTED ? (int)perm[slot0 + t] : (int)(slot0 + t);
        s_eidx[t] = e;
        s_dst[t] = edst[e];
    }
    __syncthreads();

    // ---- etype B-fragments straight to registers (no LDS) ----
    short8 etH[2][2], etL[2][2];                  // [k2][m]
    #pragma unroll
    for (int k2 = 0; k2 < 2; ++k2) {
        #pragma unroll
        for (int m = 0; m < 2; ++m) {
            const float* rowp = etype + (size_t)s_eidx[m * 16 + ln15] * 64 + k2 * 32 + g * 8;
            float4 v0 = *(const float4*)rowp;
            float4 v1 = *(const float4*)(rowp + 4);
            unsigned h0 = cvtpk(v0.x, v0.y), h1 = cvtpk(v0.z, v0.w);
            unsigned h2 = cvtpk(v1.x, v1.y), h3 = cvtpk(v1.z, v1.w);
            float l0 = v0.x - lowf(h0), l1 = v0.y - highf(h0);
            float l2 = v0.z - lowf(h1), l3 = v0.w - highf(h1);
            float l4 = v1.x - lowf(h2), l5 = v1.y - highf(h2);
            float l6 = v1.z - lowf(h3), l7 = v1.w - highf(h3);
            etH[k2][m] = mk8(h0, h1, h2, h3);
            etL[k2][m] = mk8(cvtpk(l0, l1), cvtpk(l2, l3), cvtpk(l4, l5), cvtpk(l6, l7));
        }
    }

    // ---- geometry (threads 0..63) -> geom_t[b][gi][e]; mask (wave 1) ----
    if (t < EPB * 2) {
        int e = t >> 1, b = t & 1;
        int sn = esrc[s_eidx[e]], dn = s_dst[e];
        const float* xp = nemb + ((size_t)b * NN + sn) * 3;
        const float* yp = nemb + ((size_t)b * NN + dn) * 3;
        float x0 = xp[0], x1 = xp[1], x2 = xp[2];
        float y0 = yp[0], y1 = yp[1], y2 = yp[2];
        const float inv3 = 0.5773502691896258f;
        const float inv2 = 0.7071067811865476f;
        const float inv6 = 0.4082482904638630f;
        geom_t[b][0][e] = (x0*y0 + x1*y1 + x2*y2) * inv3;
        geom_t[b][1][e] = (x1*y2 - x2*y1) * inv2;
        geom_t[b][2][e] = (x2*y0 - x0*y2) * inv2;
        geom_t[b][3][e] = (x0*y1 - x1*y0) * inv2;
        geom_t[b][4][e] = (x0*y1 + x1*y0) * inv2;
        geom_t[b][5][e] = (x1*y2 + x2*y1) * inv2;
        geom_t[b][6][e] = (x0*y2 + x2*y0) * inv2;
        geom_t[b][7][e] = (x0*y0 - x1*y1) * inv2;
        geom_t[b][8][e] = (2.0f*x2*y2 - x0*y0 - x1*y1) * inv6;
    } else if (t < 128) {
        int l = t - 64, e = l & 31;
        bool flag = (e > 0) && (s_dst[e] != s_dst[e - 1]);
        unsigned long long bal = __ballot(flag);
        if (l == 0) s_mask = (unsigned)bal;
    }

    // layer-2 accumulators persist across all four quarters
    const int m2 = w >> 1, nb = 3 * (w & 1);
    f32x4 acc2[3];
    #pragma unroll
    for (int n = 0; n < 3; ++n)
        #pragma unroll
        for (int r = 0; r < 4; ++r) acc2[n][r] = 0.f;

    #pragma unroll
    for (int qt = 0; qt < 4; ++qt) {
        // ---- layer 1 (quarter), transposed: wave w owns n-tile 4*qt + w ----
        f32x4 acc1[2];
        #pragma unroll
        for (int m = 0; m < 2; ++m)
            #pragma unroll
            for (int r = 0; r < 4; ++r) acc1[m][r] = 0.f;

        #pragma unroll
        for (int k2 = 0; k2 < 2; ++k2) {
            int idx = ((k2 * 16 + 4 * qt + w) * 64 + lane) * 8;
            short8 wah = *(const short8*)(w1h + idx);   // A-operand (W1 frag)
            short8 wal = *(const short8*)(w1l + idx);
            #pragma unroll
            for (int m = 0; m < 2; ++m) {
                acc1[m] = __builtin_amdgcn_mfma_f32_16x16x32_bf16(wah, etH[k2][m], acc1[m], 0, 0, 0);
                acc1[m] = __builtin_amdgcn_mfma_f32_16x16x32_bf16(wal, etH[k2][m], acc1[m], 0, 0, 0);
                acc1[m] = __builtin_amdgcn_mfma_f32_16x16x32_bf16(wah, etL[k2][m], acc1[m], 0, 0, 0);
            }
        }

        // ---- silu + packed split -> h quarter [e][k-local] (uint2 stores) ----
        #pragma unroll
        for (int m = 0; m < 2; ++m) {
            float s0, s1, s2, s3;
            {
                float p0 = acc1[m][0], p1 = acc1[m][1], p2 = acc1[m][2], p3 = acc1[m][3];
                s0 = p0 * __builtin_amdgcn_rcpf(1.f + __expf(-p0));
                s1 = p1 * __builtin_amdgcn_rcpf(1.f + __expf(-p1));
                s2 = p2 * __builtin_amdgcn_rcpf(1.f + __expf(-p2));
                s3 = p3 * __builtin_amdgcn_rcpf(1.f + __expf(-p3));
            }
            unsigned hp0 = cvtpk(s0, s1), hp1 = cvtpk(s2, s3);
            float lo0 = s0 - lowf(hp0), lo1 = s1 - highf(hp0);
            float lo2 = s2 - lowf(hp1), lo3 = s3 - highf(hp1);
            unsigned lp0 = cvtpk(lo0, lo1), lp1 = cvtpk(lo2, lo3);
            int e = m * 16 + ln15;
            int boff = e * 128 + ((w * 32 + g * 8) ^ ((ln15 & 7) << 4));
            *(uint2*)((char*)U.a2h + boff) = make_uint2(hp0, hp1);
            *(uint2*)((char*)U.a2l + boff) = make_uint2(lp0, lp1);
        }
        __syncthreads();

        // ---- layer 2 (quarter): k-steps kg = 2*qt, 2*qt+1 ----
        #pragma unroll
        for (int kk = 0; kk < 2; ++kk) {
            int kg = 2 * qt + kk;
            short8 bh[3], bl[3];
            #pragma unroll
            for (int n = 0; n < 3; ++n) {
                int idx = ((kg * 6 + nb + n) * 64 + lane) * 8;
                bh[n] = *(const short8*)(w2h + idx);
                bl[n] = *(const short8*)(w2l + idx);
            }
            int row = m2 * 16 + ln15;
            int boff = row * 128 + ((kk * 64 + g * 16) ^ ((ln15 & 7) << 4));
            short8 ah = *(const short8*)((const char*)U.a2h + boff);
            short8 al = *(const short8*)((const char*)U.a2l + boff);
            #pragma unroll
            for (int n = 0; n < 3; ++n) {
                acc2[n] = __builtin_amdgcn_mfma_f32_16x16x32_bf16(ah, bh[n], acc2[n], 0, 0, 0);
                acc2[n] = __builtin_amdgcn_mfma_f32_16x16x32_bf16(ah, bl[n], acc2[n], 0, 0, 0);
                acc2[n] = __builtin_amdgcn_mfma_f32_16x16x32_bf16(al, bh[n], acc2[n], 0, 0, 0);
            }
        }
        __syncthreads();   // a2 consumed; next quarter (or sw overlay) may overwrite
    }

    // ---- write w transposed to LDS: sw[c][e], stride 36 (16B-aligned rows) ----
    #pragma unroll
    for (int n = 0; n < 3; ++n) {
        int c = (nb + n) * 16 + ln15;
        #pragma unroll
        for (int r = 0; r < 4; ++r) {
            int e = m2 * 16 + g * 4 + r;
            U.sw[c * 36 + e] = acc2[n][r];
        }
    }
    __syncthreads();

    // ---- tensor product + run-grouped scatter (vector LDS reads) ----
    {
        unsigned mask = __builtin_amdgcn_readfirstlane(s_mask);
        for (int idx = t; idx < NCH * 2; idx += 256) {
            int b = idx >= NCH;
            int c = idx - b * NCH;
            unsigned wi, gi;
            if (c < 32)       { wi = c;                          gi = 0; }
            else if (c < 128) { unsigned q = c - 32;  wi = 32 + q / 3u; gi = 1 + q % 3u; }
            else              { unsigned q = c - 128; wi = 64 + q / 5u; gi = 4 + q % 5u; }
            const f32x4* wp = (const f32x4*)&U.sw[wi * 36];
            const f32x4* gp = (const f32x4*)&geom_t[b][gi][0];
            float* base = out + (size_t)b * NN * NCH + c;
            float acc = 0.f;
            int rs = 0;
            #pragma unroll
            for (int q = 0; q < 8; ++q) {
                f32x4 wv = wp[q];
                f32x4 gv = gp[q];
                #pragma unroll
                for (int j = 0; j < 4; ++j) {
                    int e = q * 4 + j;
                    if (e && (mask & (1u << e))) {
                        float* addr = base + (size_t)s_dst[e - 1] * NCH;
                        if (SORTED && rs > 0) *addr = acc;     // interior run: exclusive
                        else atomicAdd(addr, acc);             // boundary run
                        acc = 0.f; rs = e;
                    }
                    acc = fmaf(wv[j], gv[j], acc);
                }
            }
            atomicAdd(base + (size_t)s_dst[EPB - 1] * NCH, acc);   // last run
        }
    }
}

extern "C" void kernel_launch(void* const* d_in, const int* in_sizes, int n_in,
                              void* d_out, int out_size, void* d_ws, size_t ws_size,
                              hipStream_t stream) {
    const int*   esrc  = (const int*)d_in[0];
    const int*   edst  = (const int*)d_in[1];
    const float* nemb  = (const float*)d_in[2];
    const float* etype = (const float*)d_in[3];
    const float* W1    = (const float*)d_in[4];
    const float* W2    = (const float*)d_in[5];
    float* out = (float*)d_out;

    hipMemsetAsync(out, 0, (size_t)out_size * sizeof(float), stream);

    unsigned short* w1h = (unsigned short*)d_ws;
    unsigned short* w1l = w1h + W1FRAG;
    unsigned short* w2h = w1l + W1FRAG;
    unsigned short* w2l = w2h + W2FRAG;
    const size_t frag_bytes = (size_t)(2 * W1FRAG + 2 * W2FRAG) * sizeof(unsigned short);

    k_wfrag<<<(W1FRAG + W2FRAG + 255) / 256, 256, 0, stream>>>(W1, W2, w1h, w1l, w2h, w2l);

    const size_t sort_bytes = (size_t)(2 * NBIN_PAD + EDGES) * sizeof(unsigned);
    if (ws_size >= frag_bytes + sort_bytes) {
        unsigned* cnt  = (unsigned*)((char*)d_ws + frag_bytes);
        unsigned* cur  = cnt + NBIN_PAD;
        unsigned* perm = cur + NBIN_PAD;
        hipMemsetAsync(cnt, 0, NBIN_PAD * sizeof(unsigned), stream);
        k_hist<<<(EDGES + 255) / 256, 256, 0, stream>>>(edst, cnt);
        k_scan<<<1, 1024, 0, stream>>>(cnt, cur);
        k_perm<<<(EDGES + 255) / 256, 256, 0, stream>>>(edst, cur, perm);
        conv_mfma<true><<<NBLK, 256, 0, stream>>>(
            esrc, edst, nemb, etype, w1h, w1l, w2h, w2l, perm, out);
    } else {
        conv_mfma<false><<<NBLK, 256, 0, stream>>>(
            esrc, edst, nemb, etype, w1h, w1l, w2h, w2l, nullptr, out);
    }
}

// Round 8
// 283.084 us; speedup vs baseline: 1.1385x; 1.0057x over previous
//
#include <hip/hip_runtime.h>

#define EDGES 400000
#define NN 25000
#define NCH 288
#define EPB 32          // fused-fallback + kernel-B tile
#define EPA 64          // kernel-A tile
#define NBIN_PAD 25024

#define W1FRAG 16384   // 2 k2 * 16 nt * 64 lane * 8 el
#define W2FRAG 24576   // 8 k8 * 6 nt * 64 lane * 8 el

typedef float f32x4 __attribute__((ext_vector_type(4)));
typedef short short8 __attribute__((ext_vector_type(8)));

__device__ __forceinline__ unsigned short f2bf(float x) {          // RNE
    unsigned u = __float_as_uint(x);
    unsigned r = (u + 0x7fffu + ((u >> 16) & 1u)) >> 16;
    return (unsigned short)r;
}
__device__ __forceinline__ unsigned short f2bf_t(float x) {        // truncate
    return (unsigned short)(__float_as_uint(x) >> 16);
}
__device__ __forceinline__ float bf2f(unsigned short h) {
    return __uint_as_float(((unsigned)h) << 16);
}
__device__ __forceinline__ unsigned cvtpk(float a, float b) {      // 2xf32 -> 2xbf16 RNE
    unsigned r;
    asm("v_cvt_pk_bf16_f32 %0, %1, %2" : "=v"(r) : "v"(a), "v"(b));
    return r;
}
__device__ __forceinline__ float lowf(unsigned u)  { return __uint_as_float(u << 16); }
__device__ __forceinline__ float highf(unsigned u) { return __uint_as_float(u & 0xffff0000u); }

// ---------------- weight -> fragment-order bf16 hi/lo precompute ----------------
__global__ void k_wfrag(const float* __restrict__ W1, const float* __restrict__ W2,
                        unsigned short* __restrict__ w1h, unsigned short* __restrict__ w1l,
                        unsigned short* __restrict__ w2h, unsigned short* __restrict__ w2l) {
    int i = blockIdx.x * 256 + threadIdx.x;
    if (i < W1FRAG) {
        int j = i & 7, l = (i >> 3) & 63, nt = (i >> 9) & 15, k2 = (i >> 13) & 1;
        int n = nt * 16 + (l & 15), k = k2 * 32 + ((l >> 4) * 8) + j;
        float v = W1[k * 256 + n] * 0.125f;              // fold 1/sqrt(64)
        unsigned short hb = f2bf(v);
        w1h[i] = hb; w1l[i] = f2bf_t(v - bf2f(hb));
    } else if (i < W1FRAG + W2FRAG) {
        int i2 = i - W1FRAG;
        int j = i2 & 7, l = (i2 >> 3) & 63, r = i2 >> 9;  // r in [0,48)
        int nt = r % 6, k8 = r / 6;
        int n = nt * 16 + (l & 15), k = k8 * 32 + ((l >> 4) * 8) + j;
        float v = W2[k * 96 + n] * 0.015625f;            // fold 1/sqrt(256)*1/sqrt(16)
        unsigned short hb = f2bf(v);
        w2h[i2] = hb; w2l[i2] = f2bf_t(v - bf2f(hb));
    }
}

// ---------------- counting sort (dst-ordered edges) ----------------
__global__ void k_hist(const int* __restrict__ edst, unsigned* __restrict__ cnt) {
    int i = blockIdx.x * 256 + threadIdx.x;
    if (i < EDGES) atomicAdd(&cnt[edst[i]], 1u);
}

__global__ __launch_bounds__(1024) void k_scan(const unsigned* __restrict__ cnt,
                                               unsigned* __restrict__ cur) {
    __shared__ unsigned s_wt[16];
    __shared__ unsigned s_carry;
    const int t = threadIdx.x, lane = t & 63, wid = t >> 6;
    if (t == 0) s_carry = 0u;
    __syncthreads();
    for (int base = 0; base < NN; base += 1024) {
        int i = base + t;
        unsigned v = (i < NN) ? cnt[i] : 0u;
        unsigned incl = v;
        #pragma unroll
        for (int d = 1; d < 64; d <<= 1) {
            unsigned u = __shfl_up(incl, d);
            if (lane >= d) incl += u;
        }
        if (lane == 63) s_wt[wid] = incl;
        __syncthreads();
        if (wid == 0 && lane < 16) {
            unsigned wincl = s_wt[lane];
            #pragma unroll
            for (int d = 1; d < 16; d <<= 1) {
                unsigned u = __shfl_up(wincl, d);
                if (lane >= d) wincl += u;
            }
            s_wt[lane] = wincl;
        }
        __syncthreads();
        unsigned waveoff = (wid > 0) ? s_wt[wid - 1] : 0u;
        unsigned carry = s_carry;
        if (i < NN) cur[i] = carry + waveoff + incl - v;
        __syncthreads();
        if (t == 1023) s_carry = carry + s_wt[15];
        __syncthreads();
    }
}

__global__ void k_perm(const int* __restrict__ edst, unsigned* __restrict__ cur,
                       unsigned* __restrict__ perm) {
    int i = blockIdx.x * 256 + threadIdx.x;
    if (i < EDGES) {
        unsigned p = atomicAdd(&cur[edst[i]], 1u);
        perm[p] = (unsigned)i;
    }
}

__global__ void k_perm2(const int* __restrict__ edst, const int* __restrict__ esrc,
                        unsigned* __restrict__ cur, unsigned* __restrict__ perm,
                        int* __restrict__ ssrc, int* __restrict__ sdst) {
    int i = blockIdx.x * 256 + threadIdx.x;
    if (i < EDGES) {
        int d = edst[i];
        unsigned p = atomicAdd(&cur[d], 1u);
        perm[p] = (unsigned)i;
        ssrc[p] = esrc[i];
        sdst[p] = d;
    }
}

// ---------------- kernel A: MLP GEMM (64 sorted edges/block) ----------------
__global__ __launch_bounds__(256) void k_mlp(
    const float* __restrict__ etype,
    const unsigned short* __restrict__ w1h, const unsigned short* __restrict__ w1l,
    const unsigned short* __restrict__ w2h, const unsigned short* __restrict__ w2l,
    const unsigned* __restrict__ perm,
    float* __restrict__ w_sorted)
{
    __shared__ unsigned short a1h[EPA * 64];   // 8 KB  etype hi [e][k] swizzled
    __shared__ unsigned short a1l[EPA * 64];   // 8 KB
    __shared__ unsigned short a2h[EPA * 64];   // 8 KB  h quarter hi
    __shared__ unsigned short a2l[EPA * 64];   // 8 KB
    __shared__ int s_eidx[EPA];

    const int t = threadIdx.x;
    const int lane = t & 63, w = t >> 6;
    const int g = lane >> 4, ln15 = lane & 15;
    const size_t slot0 = (size_t)blockIdx.x * EPA;

    if (t < EPA) s_eidx[t] = (int)perm[slot0 + t];
    __syncthreads();

    // ---- stage etype tile (64 rows) -> bf16 hi/lo, XOR-swizzled ----
    #pragma unroll
    for (int i = 0; i < 4; ++i) {
        int f4 = t + 256 * i;                  // 0..1023
        int row = f4 >> 4, q = f4 & 15;
        const float4* src = (const float4*)(etype + (size_t)s_eidx[row] * 64);
        float4 v = src[q];
        unsigned hp01 = cvtpk(v.x, v.y), hp23 = cvtpk(v.z, v.w);
        float lo0 = v.x - lowf(hp01), lo1 = v.y - highf(hp01);
        float lo2 = v.z - lowf(hp23), lo3 = v.w - highf(hp23);
        unsigned lp01 = cvtpk(lo0, lo1), lp23 = cvtpk(lo2, lo3);
        int boff = row * 128 + ((q * 8) ^ ((row & 7) << 4));
        *(uint2*)((char*)a1h + boff) = make_uint2(hp01, hp23);
        *(uint2*)((char*)a1l + boff) = make_uint2(lp01, lp23);
    }
    __syncthreads();

    const int mh = w & 1, nb = 3 * (w >> 1);
    f32x4 acc2[2][3];
    #pragma unroll
    for (int mm = 0; mm < 2; ++mm)
        #pragma unroll
        for (int n = 0; n < 3; ++n)
            #pragma unroll
            for (int r = 0; r < 4; ++r) acc2[mm][n][r] = 0.f;

    #pragma unroll
    for (int qt = 0; qt < 4; ++qt) {
        // ---- layer 1 (quarter), transposed: wave w owns n-tile 4*qt + w ----
        f32x4 acc1[4];
        #pragma unroll
        for (int m = 0; m < 4; ++m)
            #pragma unroll
            for (int r = 0; r < 4; ++r) acc1[m][r] = 0.f;

        #pragma unroll
        for (int k2 = 0; k2 < 2; ++k2) {
            int idx = ((k2 * 16 + 4 * qt + w) * 64 + lane) * 8;
            short8 wah = *(const short8*)(w1h + idx);
            short8 wal = *(const short8*)(w1l + idx);
            #pragma unroll
            for (int m = 0; m < 4; ++m) {
                int row = m * 16 + ln15;
                int boff = row * 128 + (((k2 * 64) + g * 16) ^ ((row & 7) << 4));
                short8 eth = *(const short8*)((const char*)a1h + boff);
                short8 etl = *(const short8*)((const char*)a1l + boff);
                acc1[m] = __builtin_amdgcn_mfma_f32_16x16x32_bf16(wah, eth, acc1[m], 0, 0, 0);
                acc1[m] = __builtin_amdgcn_mfma_f32_16x16x32_bf16(wal, eth, acc1[m], 0, 0, 0);
                acc1[m] = __builtin_amdgcn_mfma_f32_16x16x32_bf16(wah, etl, acc1[m], 0, 0, 0);
            }
        }

        // ---- silu + packed split -> h quarter ----
        #pragma unroll
        for (int m = 0; m < 4; ++m) {
            float p0 = acc1[m][0], p1 = acc1[m][1], p2 = acc1[m][2], p3 = acc1[m][3];
            float s0 = p0 * __builtin_amdgcn_rcpf(1.f + __expf(-p0));
            float s1 = p1 * __builtin_amdgcn_rcpf(1.f + __expf(-p1));
            float s2 = p2 * __builtin_amdgcn_rcpf(1.f + __expf(-p2));
            float s3 = p3 * __builtin_amdgcn_rcpf(1.f + __expf(-p3));
            unsigned hp0 = cvtpk(s0, s1), hp1 = cvtpk(s2, s3);
            float lo0 = s0 - lowf(hp0), lo1 = s1 - highf(hp0);
            float lo2 = s2 - lowf(hp1), lo3 = s3 - highf(hp1);
            unsigned lp0 = cvtpk(lo0, lo1), lp1 = cvtpk(lo2, lo3);
            int e = m * 16 + ln15;
            int boff = e * 128 + ((w * 32 + g * 8) ^ ((ln15 & 7) << 4));
            *(uint2*)((char*)a2h + boff) = make_uint2(hp0, hp1);
            *(uint2*)((char*)a2l + boff) = make_uint2(lp0, lp1);
        }
        __syncthreads();

        // ---- layer 2 (quarter): k-steps kg = 2*qt, 2*qt+1 ----
        #pragma unroll
        for (int kk = 0; kk < 2; ++kk) {
            int kg = 2 * qt + kk;
            short8 bh[3], bl[3];
            #pragma unroll
            for (int n = 0; n < 3; ++n) {
                int idx = ((kg * 6 + nb + n) * 64 + lane) * 8;
                bh[n] = *(const short8*)(w2h + idx);
                bl[n] = *(const short8*)(w2l + idx);
            }
            #pragma unroll
            for (int mm = 0; mm < 2; ++mm) {
                int row = (2 * mh + mm) * 16 + ln15;
                int boff = row * 128 + ((kk * 64 + g * 16) ^ ((ln15 & 7) << 4));
                short8 ah = *(const short8*)((const char*)a2h + boff);
                short8 al = *(const short8*)((const char*)a2l + boff);
                #pragma unroll
                for (int n = 0; n < 3; ++n) {
                    acc2[mm][n] = __builtin_amdgcn_mfma_f32_16x16x32_bf16(ah, bh[n], acc2[mm][n], 0, 0, 0);
                    acc2[mm][n] = __builtin_amdgcn_mfma_f32_16x16x32_bf16(ah, bl[n], acc2[mm][n], 0, 0, 0);
                    acc2[mm][n] = __builtin_amdgcn_mfma_f32_16x16x32_bf16(al, bh[n], acc2[mm][n], 0, 0, 0);
                }
            }
        }
        __syncthreads();   // a2 consumed; next quarter overwrites
    }

    // ---- write w_sorted[slot][c], coalesced across ln15 ----
    #pragma unroll
    for (int mm = 0; mm < 2; ++mm) {
        #pragma unroll
        for (int n = 0; n < 3; ++n) {
            int c = (nb + n) * 16 + ln15;
            #pragma unroll
            for (int r = 0; r < 4; ++r) {
                int e = (2 * mh + mm) * 16 + g * 4 + r;
                w_sorted[(slot0 + e) * 96 + c] = acc2[mm][n][r];
            }
        }
    }
}

// ---------------- kernel B: tensor product + run-grouped scatter ----------------
__global__ __launch_bounds__(256) void k_tp(
    const int* __restrict__ ssrc, const int* __restrict__ sdst,
    const float* __restrict__ nemb, const float* __restrict__ w_sorted,
    float* __restrict__ out)
{
    __shared__ __align__(16) float sw[96 * 36];        // [c][e], stride 36
    __shared__ __align__(16) float geom_t[2][9][EPB];  // [b][gi][e]
    __shared__ int s_dst[EPB];
    __shared__ unsigned s_mask;

    const int t = threadIdx.x;
    const size_t slot0 = (size_t)blockIdx.x * EPB;

    // ---- stage w tile (12 KB contiguous) and transpose into sw ----
    {
        const float4* w4 = (const float4*)w_sorted + slot0 * 24;
        #pragma unroll
        for (int i = 0; i < 3; ++i) {
            int j = t + 256 * i;               // 0..767
            int e = j / 24, c4 = j % 24;
            float4 v = w4[j];
            sw[(c4 * 4 + 0) * 36 + e] = v.x;
            sw[(c4 * 4 + 1) * 36 + e] = v.y;
            sw[(c4 * 4 + 2) * 36 + e] = v.z;
            sw[(c4 * 4 + 3) * 36 + e] = v.w;
        }
    }
    if (t < EPB) s_dst[t] = sdst[slot0 + t];

    // ---- geometry (wave 0) / boundary mask (wave 1) ----
    if (t < EPB * 2) {
        int e = t >> 1, b = t & 1;
        int sn = ssrc[slot0 + e], dn = sdst[slot0 + e];
        const float* xp = nemb + ((size_t)b * NN + sn) * 3;
        const float* yp = nemb + ((size_t)b * NN + dn) * 3;
        float x0 = xp[0], x1 = xp[1], x2 = xp[2];
        float y0 = yp[0], y1 = yp[1], y2 = yp[2];
        const float inv3 = 0.5773502691896258f;
        const float inv2 = 0.7071067811865476f;
        const float inv6 = 0.4082482904638630f;
        geom_t[b][0][e] = (x0*y0 + x1*y1 + x2*y2) * inv3;
        geom_t[b][1][e] = (x1*y2 - x2*y1) * inv2;
        geom_t[b][2][e] = (x2*y0 - x0*y2) * inv2;
        geom_t[b][3][e] = (x0*y1 - x1*y0) * inv2;
        geom_t[b][4][e] = (x0*y1 + x1*y0) * inv2;
        geom_t[b][5][e] = (x1*y2 + x2*y1) * inv2;
        geom_t[b][6][e] = (x0*y2 + x2*y0) * inv2;
        geom_t[b][7][e] = (x0*y0 - x1*y1) * inv2;
        geom_t[b][8][e] = (2.0f*x2*y2 - x0*y0 - x1*y1) * inv6;
    } else if (t < 128) {
        int l = t - 64, e = l & 31;
        bool flag = (e > 0) && (sdst[slot0 + e] != sdst[slot0 + e - 1]);
        unsigned long long bal = __ballot(flag);
        if (l == 0) s_mask = (unsigned)bal;
    }
    __syncthreads();

    // ---- TP + run-grouped scatter ----
    unsigned mask = __builtin_amdgcn_readfirstlane(s_mask);
    for (int idx = t; idx < NCH * 2; idx += 256) {
        int b = idx >= NCH;
        int c = idx - b * NCH;
        unsigned wi, gi;
        if (c < 32)       { wi = c;                          gi = 0; }
        else if (c < 128) { unsigned q = c - 32;  wi = 32 + q / 3u; gi = 1 + q % 3u; }
        else              { unsigned q = c - 128; wi = 64 + q / 5u; gi = 4 + q % 5u; }
        const f32x4* wp = (const f32x4*)&sw[wi * 36];
        const f32x4* gp = (const f32x4*)&geom_t[b][gi][0];
        float* base = out + (size_t)b * NN * NCH + c;
        float acc = 0.f;
        int rs = 0;
        #pragma unroll
        for (int q = 0; q < 8; ++q) {
            f32x4 wv = wp[q];
            f32x4 gv = gp[q];
            #pragma unroll
            for (int j = 0; j < 4; ++j) {
                int e = q * 4 + j;
                if (e && (mask & (1u << e))) {
                    float* addr = base + (size_t)s_dst[e - 1] * NCH;
                    if (rs > 0) *addr = acc;           // interior run: exclusive owner
                    else atomicAdd(addr, acc);         // first run: boundary
                    acc = 0.f; rs = e;
                }
                acc = fmaf(wv[j], gv[j], acc);
            }
        }
        atomicAdd(base + (size_t)s_dst[EPB - 1] * NCH, acc);   // last run: boundary
    }
}

// ---------------- fused fallback (round-7 kernel, used when ws too small) ----------------
struct SMemF {
    union {
        struct __align__(16) {
            unsigned short a2h[EPB * 64];
            unsigned short a2l[EPB * 64];
        };
        float sw[96 * 36];
    };
};

template <bool SORTED>
__global__ __launch_bounds__(256) void conv_fused_fb(
    const int* __restrict__ esrc, const int* __restrict__ edst,
    const float* __restrict__ nemb, const float* __restrict__ etype,
    const unsigned short* __restrict__ w1h, const unsigned short* __restrict__ w1l,
    const unsigned short* __restrict__ w2h, const unsigned short* __restrict__ w2l,
    const unsigned* __restrict__ perm,
    float* __restrict__ out)
{
    __shared__ SMemF U;
    __shared__ __align__(16) float geom_t[2][9][EPB];
    __shared__ int s_eidx[EPB], s_dst[EPB];
    __shared__ unsigned s_mask;

    const int t = threadIdx.x;
    const int lane = t & 63, w = t >> 6;
    const int g = lane >> 4, ln15 = lane & 15;
    const size_t slot0 = (size_t)blockIdx.x * EPB;

    if (t < EPB) {
        int e = SORTED ? (int)perm[slot0 + t] : (int)(slot0 + t);
        s_eidx[t] = e;
        s_dst[t] = edst[e];
    }
    __syncthreads();

    short8 etH[2][2], etL[2][2];
    #pragma unroll
    for (int k2 = 0; k2 < 2; ++k2) {
        #pragma unroll
        for (int m = 0; m < 2; ++m) {
            const float* rowp = etype + (size_t)s_eidx[m * 16 + ln15] * 64 + k2 * 32 + g * 8;
            float4 v0 = *(const float4*)rowp;
            float4 v1 = *(const float4*)(rowp + 4);
            unsigned h0 = cvtpk(v0.x, v0.y), h1 = cvtpk(v0.z, v0.w);
            unsigned h2 = cvtpk(v1.x, v1.y), h3 = cvtpk(v1.z, v1.w);
            float l0 = v0.x - lowf(h0), l1 = v0.y - highf(h0);
            float l2 = v0.z - lowf(h1), l3 = v0.w - highf(h1);
            float l4 = v1.x - lowf(h2), l5 = v1.y - highf(h2);
            float l6 = v1.z - lowf(h3), l7 = v1.w - highf(h3);
            union { unsigned u[4]; short8 s; } xh, xl;
            xh.u[0] = h0; xh.u[1] = h1; xh.u[2] = h2; xh.u[3] = h3;
            xl.u[0] = cvtpk(l0, l1); xl.u[1] = cvtpk(l2, l3);
            xl.u[2] = cvtpk(l4, l5); xl.u[3] = cvtpk(l6, l7);
            etH[k2][m] = xh.s; etL[k2][m] = xl.s;
        }
    }

    if (t < EPB * 2) {
        int e = t >> 1, b = t & 1;
        int sn = esrc[s_eidx[e]], dn = s_dst[e];
        const float* xp = nemb + ((size_t)b * NN + sn) * 3;
        const float* yp = nemb + ((size_t)b * NN + dn) * 3;
        float x0 = xp[0], x1 = xp[1], x2 = xp[2];
        float y0 = yp[0], y1 = yp[1], y2 = yp[2];
        const float inv3 = 0.5773502691896258f;
        const float inv2 = 0.7071067811865476f;
        const float inv6 = 0.4082482904638630f;
        geom_t[b][0][e] = (x0*y0 + x1*y1 + x2*y2) * inv3;
        geom_t[b][1][e] = (x1*y2 - x2*y1) * inv2;
        geom_t[b][2][e] = (x2*y0 - x0*y2) * inv2;
        geom_t[b][3][e] = (x0*y1 - x1*y0) * inv2;
        geom_t[b][4][e] = (x0*y1 + x1*y0) * inv2;
        geom_t[b][5][e] = (x1*y2 + x2*y1) * inv2;
        geom_t[b][6][e] = (x0*y2 + x2*y0) * inv2;
        geom_t[b][7][e] = (x0*y0 - x1*y1) * inv2;
        geom_t[b][8][e] = (2.0f*x2*y2 - x0*y0 - x1*y1) * inv6;
    } else if (t < 128) {
        int l = t - 64, e = l & 31;
        bool flag = (e > 0) && (s_dst[e] != s_dst[e - 1]);
        unsigned long long bal = __ballot(flag);
        if (l == 0) s_mask = (unsigned)bal;
    }

    const int m2 = w >> 1, nb = 3 * (w & 1);
    f32x4 acc2[3];
    #pragma unroll
    for (int n = 0; n < 3; ++n)
        #pragma unroll
        for (int r = 0; r < 4; ++r) acc2[n][r] = 0.f;

    #pragma unroll
    for (int qt = 0; qt < 4; ++qt) {
        f32x4 acc1[2];
        #pragma unroll
        for (int m = 0; m < 2; ++m)
            #pragma unroll
            for (int r = 0; r < 4; ++r) acc1[m][r] = 0.f;

        #pragma unroll
        for (int k2 = 0; k2 < 2; ++k2) {
            int idx = ((k2 * 16 + 4 * qt + w) * 64 + lane) * 8;
            short8 wah = *(const short8*)(w1h + idx);
            short8 wal = *(const short8*)(w1l + idx);
            #pragma unroll
            for (int m = 0; m < 2; ++m) {
                acc1[m] = __builtin_amdgcn_mfma_f32_16x16x32_bf16(wah, etH[k2][m], acc1[m], 0, 0, 0);
                acc1[m] = __builtin_amdgcn_mfma_f32_16x16x32_bf16(wal, etH[k2][m], acc1[m], 0, 0, 0);
                acc1[m] = __builtin_amdgcn_mfma_f32_16x16x32_bf16(wah, etL[k2][m], acc1[m], 0, 0, 0);
            }
        }

        #pragma unroll
        for (int m = 0; m < 2; ++m) {
            float p0 = acc1[m][0], p1 = acc1[m][1], p2 = acc1[m][2], p3 = acc1[m][3];
            float s0 = p0 * __builtin_amdgcn_rcpf(1.f + __expf(-p0));
            float s1 = p1 * __builtin_amdgcn_rcpf(1.f + __expf(-p1));
            float s2 = p2 * __builtin_amdgcn_rcpf(1.f + __expf(-p2));
            float s3 = p3 * __builtin_amdgcn_rcpf(1.f + __expf(-p3));
            unsigned hp0 = cvtpk(s0, s1), hp1 = cvtpk(s2, s3);
            float lo0 = s0 - lowf(hp0), lo1 = s1 - highf(hp0);
            float lo2 = s2 - lowf(hp1), lo3 = s3 - highf(hp1);
            unsigned lp0 = cvtpk(lo0, lo1), lp1 = cvtpk(lo2, lo3);
            int e = m * 16 + ln15;
            int boff = e * 128 + ((w * 32 + g * 8) ^ ((ln15 & 7) << 4));
            *(uint2*)((char*)U.a2h + boff) = make_uint2(hp0, hp1);
            *(uint2*)((char*)U.a2l + boff) = make_uint2(lp0, lp1);
        }
        __syncthreads();

        #pragma unroll
        for (int kk = 0; kk < 2; ++kk) {
            int kg = 2 * qt + kk;
            short8 bh[3], bl[3];
            #pragma unroll
            for (int n = 0; n < 3; ++n) {
                int idx = ((kg * 6 + nb + n) * 64 + lane) * 8;
                bh[n] = *(const short8*)(w2h + idx);
                bl[n] = *(const short8*)(w2l + idx);
            }
            int row = m2 * 16 + ln15;
            int boff = row * 128 + ((kk * 64 + g * 16) ^ ((ln15 & 7) << 4));
            short8 ah = *(const short8*)((const char*)U.a2h + boff);
            short8 al = *(const short8*)((const char*)U.a2l + boff);
            #pragma unroll
            for (int n = 0; n < 3; ++n) {
                acc2[n] = __builtin_amdgcn_mfma_f32_16x16x32_bf16(ah, bh[n], acc2[n], 0, 0, 0);
                acc2[n] = __builtin_amdgcn_mfma_f32_16x16x32_bf16(ah, bl[n], acc2[n], 0, 0, 0);
                acc2[n] = __builtin_amdgcn_mfma_f32_16x16x32_bf16(al, bh[n], acc2[n], 0, 0, 0);
            }
        }
        __syncthreads();
    }

    #pragma unroll
    for (int n = 0; n < 3; ++n) {
        int c = (nb + n) * 16 + ln15;
        #pragma unroll
        for (int r = 0; r < 4; ++r) {
            int e = m2 * 16 + g * 4 + r;
            U.sw[c * 36 + e] = acc2[n][r];
        }
    }
    __syncthreads();

    {
        unsigned mask = __builtin_amdgcn_readfirstlane(s_mask);
        for (int idx = t; idx < NCH * 2; idx += 256) {
            int b = idx >= NCH;
            int c = idx - b * NCH;
            unsigned wi, gi;
            if (c < 32)       { wi = c;                          gi = 0; }
            else if (c < 128) { unsigned q = c - 32;  wi = 32 + q / 3u; gi = 1 + q % 3u; }
            else              { unsigned q = c - 128; wi = 64 + q / 5u; gi = 4 + q % 5u; }
            const f32x4* wp = (const f32x4*)&U.sw[wi * 36];
            const f32x4* gp = (const f32x4*)&geom_t[b][gi][0];
            float* base = out + (size_t)b * NN * NCH + c;
            float acc = 0.f;
            int rs = 0;
            #pragma unroll
            for (int q = 0; q < 8; ++q) {
                f32x4 wv = wp[q];
                f32x4 gv = gp[q];
                #pragma unroll
                for (int j = 0; j < 4; ++j) {
                    int e = q * 4 + j;
                    if (e && (mask & (1u << e))) {
                        float* addr = base + (size_t)s_dst[e - 1] * NCH;
                        if (SORTED && rs > 0) *addr = acc;
                        else atomicAdd(addr, acc);
                        acc = 0.f; rs = e;
                    }
                    acc = fmaf(wv[j], gv[j], acc);
                }
            }
            atomicAdd(base + (size_t)s_dst[EPB - 1] * NCH, acc);
        }
    }
}

extern "C" void kernel_launch(void* const* d_in, const int* in_sizes, int n_in,
                              void* d_out, int out_size, void* d_ws, size_t ws_size,
                              hipStream_t stream) {
    const int*   esrc  = (const int*)d_in[0];
    const int*   edst  = (const int*)d_in[1];
    const float* nemb  = (const float*)d_in[2];
    const float* etype = (const float*)d_in[3];
    const float* W1    = (const float*)d_in[4];
    const float* W2    = (const float*)d_in[5];
    float* out = (float*)d_out;

    hipMemsetAsync(out, 0, (size_t)out_size * sizeof(float), stream);

    const size_t frag_bytes = (size_t)(2 * W1FRAG + 2 * W2FRAG) * sizeof(unsigned short);
    unsigned short* w1h = (unsigned short*)d_ws;
    unsigned short* w1l = w1h + W1FRAG;
    unsigned short* w2h = w1l + W1FRAG;
    unsigned short* w2l = w2h + W2FRAG;

    size_t o_cnt  = frag_bytes;
    size_t o_cur  = o_cnt + (size_t)NBIN_PAD * 4;
    size_t o_perm = o_cur + (size_t)NBIN_PAD * 4;
    size_t o_ssrc = o_perm + (size_t)EDGES * 4;
    size_t o_sdst = o_ssrc + (size_t)EDGES * 4;
    size_t o_w    = (o_sdst + (size_t)EDGES * 4 + 255) & ~(size_t)255;
    size_t need_split = o_w + (size_t)EDGES * 96 * 4;
    size_t need_sort  = o_perm + (size_t)EDGES * 4;

    k_wfrag<<<(W1FRAG + W2FRAG + 255) / 256, 256, 0, stream>>>(W1, W2, w1h, w1l, w2h, w2l);

    if (ws_size >= need_split) {
        unsigned* cnt   = (unsigned*)((char*)d_ws + o_cnt);
        unsigned* cur   = (unsigned*)((char*)d_ws + o_cur);
        unsigned* perm  = (unsigned*)((char*)d_ws + o_perm);
        int* ssrc       = (int*)((char*)d_ws + o_ssrc);
        int* sdst       = (int*)((char*)d_ws + o_sdst);
        float* w_sorted = (float*)((char*)d_ws + o_w);

        hipMemsetAsync(cnt, 0, (size_t)NBIN_PAD * 4, stream);
        k_hist<<<(EDGES + 255) / 256, 256, 0, stream>>>(edst, cnt);
        k_scan<<<1, 1024, 0, stream>>>(cnt, cur);
        k_perm2<<<(EDGES + 255) / 256, 256, 0, stream>>>(edst, esrc, cur, perm, ssrc, sdst);
        k_mlp<<<EDGES / EPA, 256, 0, stream>>>(etype, w1h, w1l, w2h, w2l, perm, w_sorted);
        k_tp<<<EDGES / EPB, 256, 0, stream>>>(ssrc, sdst, nemb, w_sorted, out);
    } else if (ws_size >= need_sort) {
        unsigned* cnt  = (unsigned*)((char*)d_ws + o_cnt);
        unsigned* cur  = (unsigned*)((char*)d_ws + o_cur);
        unsigned* perm = (unsigned*)((char*)d_ws + o_perm);
        hipMemsetAsync(cnt, 0, (size_t)NBIN_PAD * 4, stream);
        k_hist<<<(EDGES + 255) / 256, 256, 0, stream>>>(edst, cnt);
        k_scan<<<1, 1024, 0, stream>>>(cnt, cur);
        k_perm<<<(EDGES + 255) / 256, 256, 0, stream>>>(edst, cur, perm);
        conv_fused_fb<true><<<EDGES / EPB, 256, 0, stream>>>(
            esrc, edst, nemb, etype, w1h, w1l, w2h, w2l, perm, out);
    } else {
        conv_fused_fb<false><<<EDGES / EPB, 256, 0, stream>>>(
            esrc, edst, nemb, etype, w1h, w1l, w2h, w2l, nullptr, out);
    }
}